// Round 1
// baseline (1596.978 us; speedup 1.0000x reference)
//
#include <hip/hip_runtime.h>
#include <stdint.h>

// LeWin window attention, fused: qkv GEMM -> per-head attention -> proj GEMM.
// One block per window (8192 windows of 64 tokens x 256 dim), 512 threads.
// All matmuls via v_mfma_f32_16x16x32_bf16, fp32 accumulate, fp32 softmax.

typedef __attribute__((ext_vector_type(8))) short bf16x8;
typedef __attribute__((ext_vector_type(4))) float f32x4;

#define QK_LD 520   // row stride (elems) of q|k LDS tile [64][512] (+8 pad: bank offset 4/row)
#define VT_LD 72    // row stride of v-transposed tile [256][64] (+8 pad)
#define P_LD  72    // row stride of P tile [64][64] (+8 pad)
#define X_LD  264   // row stride of x / attn-out tile [64][256] (+8 pad)
#define SMEM_ELEMS (64 * QK_LD + 256 * VT_LD + 2 * 64 * P_LD + 64 * X_LD)
#define SMEM_BYTES (SMEM_ELEMS * 2)

__device__ __forceinline__ unsigned short f2bf(float x) {   // round-to-nearest-even
  union { float f; unsigned int u; } v; v.f = x;
  return (unsigned short)((v.u + 0x7fffu + ((v.u >> 16) & 1u)) >> 16);
}
__device__ __forceinline__ float bf2f(unsigned short u) {
  union { unsigned int u; float f; } v; v.u = ((unsigned int)u) << 16;
  return v.f;
}

__global__ void prep_kernel(const float* __restrict__ qkv_w,
                            const float* __restrict__ proj_w,
                            const float* __restrict__ table,
                            const int* __restrict__ idx,
                            unsigned short* __restrict__ wq,
                            unsigned short* __restrict__ wp,
                            unsigned short* __restrict__ bm) {
  int i = blockIdx.x * 256 + threadIdx.x;          // grid sized to exactly 294912
  if (i < 196608) {
    wq[i] = f2bf(qkv_w[i]);
  } else if (i < 262144) {
    int j = i - 196608;
    wp[j] = f2bf(proj_w[j]);
  } else {
    int k = i - 262144;                            // k = h*4096 + r*64 + c, k < 32768
    int h = k >> 12;
    int rc = k & 4095;
    bm[k] = f2bf(table[idx[rc] * 8 + h]);
  }
}

__launch_bounds__(512, 2)
__global__ void lewin_kernel(const float* __restrict__ x,
                             const unsigned short* __restrict__ wq,   // [768][256] bf16
                             const float* __restrict__ qkv_b,
                             const unsigned short* __restrict__ wp,   // [256][256] bf16
                             const float* __restrict__ proj_b,
                             const unsigned short* __restrict__ bm,   // [8][64][64] bf16
                             float* __restrict__ out) {
  extern __shared__ __align__(16) unsigned short smem[];
  unsigned short* sQK = smem;                       // [64][QK_LD]  q cols 0..255, k cols 256..511
  unsigned short* sVT = smem + 64 * QK_LD;          // [256][VT_LD] v transposed: [h*32+d][token]
  unsigned short* sP  = sVT + 256 * VT_LD;          // [2][64][P_LD] per head-set P
  unsigned short* sX  = sP + 2 * 64 * P_LD;         // [64][X_LD]   x (phase 1-2), attn-out (3-4)

  const int b    = blockIdx.x;
  const int tid  = threadIdx.x;
  const int wv   = tid >> 6;        // wave 0..7
  const int lane = tid & 63;
  const int l16  = lane & 15;
  const int quad = lane >> 4;
  const f32x4 fz = {0.0f, 0.0f, 0.0f, 0.0f};

  // ---------- Phase 1: stage x window (f32 HBM -> bf16 LDS), fully coalesced ----------
  const float* xb = x + (size_t)b * 16384;
  #pragma unroll
  for (int it = 0; it < 8; ++it) {
    int f = (it * 512 + tid) * 4;                   // flat float index in window
    float4 v = *(const float4*)(xb + f);
    int row = f >> 8, col = f & 255;
    ushort4 u;
    u.x = f2bf(v.x); u.y = f2bf(v.y); u.z = f2bf(v.z); u.w = f2bf(v.w);
    *(ushort4*)(sX + row * X_LD + col) = u;
  }
  __syncthreads();

  // ---------- Phase 2: qkv = x @ Wqkv^T (+b). Wave wv owns output cols [96*wv, 96*wv+96) ----
  bf16x8 afrag[4][8];                               // all 4 M-tiles x 8 K-steps, held in regs
  #pragma unroll
  for (int m = 0; m < 4; ++m)
    #pragma unroll
    for (int kk = 0; kk < 8; ++kk)
      afrag[m][kk] = *(const bf16x8*)(sX + (16 * m + l16) * X_LD + kk * 32 + quad * 8);

  #pragma unroll
  for (int nt = 0; nt < 6; ++nt) {
    int col = wv * 96 + nt * 16 + l16;              // global output column (0..767)
    bf16x8 bfrag[8];
    const unsigned short* wrow = wq + (size_t)col * 256 + quad * 8;
    #pragma unroll
    for (int kk = 0; kk < 8; ++kk)
      bfrag[kk] = *(const bf16x8*)(wrow + kk * 32);
    f32x4 acc[4] = {fz, fz, fz, fz};
    #pragma unroll
    for (int kk = 0; kk < 8; ++kk)
      #pragma unroll
      for (int m = 0; m < 4; ++m)
        acc[m] = __builtin_amdgcn_mfma_f32_16x16x32_bf16(afrag[m][kk], bfrag[kk], acc[m], 0, 0, 0);
    float bc = qkv_b[col];
    #pragma unroll
    for (int m = 0; m < 4; ++m) {
      int row0 = 16 * m + quad * 4;
      if (col < 512) {                              // q,k: row-major [token][col]
        #pragma unroll
        for (int r = 0; r < 4; ++r)
          sQK[(row0 + r) * QK_LD + col] = f2bf(acc[m][r] + bc);
      } else {                                      // v: transposed [col-512][token], 4 contig
        int c = col - 512;
        ushort4 u;
        u.x = f2bf(acc[m][0] + bc); u.y = f2bf(acc[m][1] + bc);
        u.z = f2bf(acc[m][2] + bc); u.w = f2bf(acc[m][3] + bc);
        *(ushort4*)(sVT + c * VT_LD + row0) = u;
      }
    }
  }
  __syncthreads();

  // ---------- Phase 3: attention. Wave -> (M-tile mt, head-set hs). No intra-loop barriers:
  // each wave reads/writes only its own 16 P rows and its own out rows/cols. ----------
  const int mt = wv & 3;
  const int hs = wv >> 2;
  unsigned short* sOut = sX;                        // x staging area is dead now
  unsigned short* myP = sP + hs * (64 * P_LD);
  const float scale = 0.17677669529663687f;         // HEAD_DIM^-0.5
  const float log2e = 1.4426950408889634f;

  #pragma unroll
  for (int hh = 0; hh < 4; ++hh) {
    int h = hs * 4 + hh;
    bf16x8 qa = *(const bf16x8*)(sQK + (16 * mt + l16) * QK_LD + h * 32 + quad * 8);
    float lg[4][4];                                 // [nt][reg]: logits row=16mt+quad*4+reg, col=nt*16+l16
    #pragma unroll
    for (int nt = 0; nt < 4; ++nt) {
      bf16x8 kb = *(const bf16x8*)(sQK + (nt * 16 + l16) * QK_LD + 256 + h * 32 + quad * 8);
      f32x4 a = fz;
      a = __builtin_amdgcn_mfma_f32_16x16x32_bf16(qa, kb, a, 0, 0, 0);
      const unsigned short* bmr = bm + (h * 64 + 16 * mt + quad * 4) * 64 + nt * 16 + l16;
      #pragma unroll
      for (int r = 0; r < 4; ++r)
        lg[nt][r] = a[r] * scale + bf2f(bmr[r * 64]);
    }
    // softmax per row (row's 64 values live in the 16 lanes of this quad, 4 per lane)
    #pragma unroll
    for (int r = 0; r < 4; ++r) {
      float m0 = fmaxf(fmaxf(lg[0][r], lg[1][r]), fmaxf(lg[2][r], lg[3][r]));
      #pragma unroll
      for (int s = 1; s < 16; s <<= 1) m0 = fmaxf(m0, __shfl_xor(m0, s, 64));
      float e0 = exp2f((lg[0][r] - m0) * log2e);
      float e1 = exp2f((lg[1][r] - m0) * log2e);
      float e2 = exp2f((lg[2][r] - m0) * log2e);
      float e3 = exp2f((lg[3][r] - m0) * log2e);
      float sum = e0 + e1 + e2 + e3;
      #pragma unroll
      for (int s = 1; s < 16; s <<= 1) sum += __shfl_xor(sum, s, 64);
      float inv = 1.0f / sum;
      unsigned short* pd = myP + (16 * mt + quad * 4 + r) * P_LD + l16;
      pd[0]  = f2bf(e0 * inv);
      pd[16] = f2bf(e1 * inv);
      pd[32] = f2bf(e2 * inv);
      pd[48] = f2bf(e3 * inv);
    }
    // PV: out_h[64x32] = P[64x64] @ V[64x32]
    f32x4 o0 = fz, o1 = fz;
    #pragma unroll
    for (int kk = 0; kk < 2; ++kk) {
      bf16x8 pa  = *(const bf16x8*)(myP + (16 * mt + l16) * P_LD + kk * 32 + quad * 8);
      bf16x8 vb0 = *(const bf16x8*)(sVT + (h * 32 + l16) * VT_LD + kk * 32 + quad * 8);
      bf16x8 vb1 = *(const bf16x8*)(sVT + (h * 32 + 16 + l16) * VT_LD + kk * 32 + quad * 8);
      o0 = __builtin_amdgcn_mfma_f32_16x16x32_bf16(pa, vb0, o0, 0, 0, 0);
      o1 = __builtin_amdgcn_mfma_f32_16x16x32_bf16(pa, vb1, o1, 0, 0, 0);
    }
    #pragma unroll
    for (int r = 0; r < 4; ++r) {
      int orow = 16 * mt + quad * 4 + r;
      sOut[orow * X_LD + h * 32 + l16]      = f2bf(o0[r]);
      sOut[orow * X_LD + h * 32 + 16 + l16] = f2bf(o1[r]);
    }
  }
  __syncthreads();

  // ---------- Phase 4: final = attn_out @ Wproj^T (+b). Wave wv owns cols [32*wv, 32*wv+32) ----
  bf16x8 of[4][8];
  #pragma unroll
  for (int m = 0; m < 4; ++m)
    #pragma unroll
    for (int kk = 0; kk < 8; ++kk)
      of[m][kk] = *(const bf16x8*)(sOut + (16 * m + l16) * X_LD + kk * 32 + quad * 8);

  float* ob = out + (size_t)b * 16384;
  #pragma unroll
  for (int nt = 0; nt < 2; ++nt) {
    int col = wv * 32 + nt * 16 + l16;
    bf16x8 bfrag[8];
    const unsigned short* wrow = wp + (size_t)col * 256 + quad * 8;
    #pragma unroll
    for (int kk = 0; kk < 8; ++kk)
      bfrag[kk] = *(const bf16x8*)(wrow + kk * 32);
    f32x4 acc[4] = {fz, fz, fz, fz};
    #pragma unroll
    for (int kk = 0; kk < 8; ++kk)
      #pragma unroll
      for (int m = 0; m < 4; ++m)
        acc[m] = __builtin_amdgcn_mfma_f32_16x16x32_bf16(of[m][kk], bfrag[kk], acc[m], 0, 0, 0);
    float pb = proj_b[col];
    #pragma unroll
    for (int m = 0; m < 4; ++m)
      #pragma unroll
      for (int r = 0; r < 4; ++r)
        ob[(16 * m + quad * 4 + r) * 256 + col] = acc[m][r] + pb;
  }
}

extern "C" void kernel_launch(void* const* d_in, const int* in_sizes, int n_in,
                              void* d_out, int out_size, void* d_ws, size_t ws_size,
                              hipStream_t stream) {
  const float* x      = (const float*)d_in[0];
  const float* qkv_w  = (const float*)d_in[1];   // [768][256]
  const float* qkv_b  = (const float*)d_in[2];   // [768]
  const float* proj_w = (const float*)d_in[3];   // [256][256]
  const float* proj_b = (const float*)d_in[4];   // [256]
  const float* table  = (const float*)d_in[5];   // [225][8]
  const int*   idx    = (const int*)d_in[6];     // [64][64]
  float* out = (float*)d_out;

  // ws layout: bf16 qkv_w (393216 B) | bf16 proj_w (131072 B) | bf16 bias [8][64][64] (65536 B)
  unsigned short* wq = (unsigned short*)d_ws;
  unsigned short* wp = wq + 196608;
  unsigned short* bm = wp + 65536;

  (void)hipFuncSetAttribute((const void*)lewin_kernel,
                            hipFuncAttributeMaxDynamicSharedMemorySize, SMEM_BYTES);

  prep_kernel<<<1152, 256, 0, stream>>>(qkv_w, proj_w, table, idx, wq, wp, bm);
  lewin_kernel<<<8192, 512, SMEM_BYTES, stream>>>(x, wq, qkv_b, wp, proj_b, bm, out);
}